// Round 1
// baseline (125.952 us; speedup 1.0000x reference)
//
#include <hip/hip_runtime.h>
#include <hip/hip_bf16.h>

#define DCONST 512
#define MAXN   512
#define NGRAPH 64

typedef __bf16 bf16x8 __attribute__((ext_vector_type(8)));
typedef float  f32x4  __attribute__((ext_vector_type(4)));
typedef float  fvec4  __attribute__((ext_vector_type(4)));

// ---------------------------------------------------------------------------
// Stage 2: scatter fp32 rows -> bf16 padded [NGRAPH][MAXN][DCONST]
// 8 elements per thread: 32B fp32 read, 16B bf16 write, fully coalesced.
// ---------------------------------------------------------------------------
__global__ void scatter_bf16(const float* __restrict__ h,
                             const int* __restrict__ gids,
                             const int* __restrict__ pids,
                             __bf16* __restrict__ padded,
                             int total)
{
    int t    = blockIdx.x * blockDim.x + threadIdx.x;
    int node = t >> 6;                 // 64 segments of 8 elems per 512-row
    if (node >= total) return;
    int seg  = t & 63;
    int g    = gids[node];
    int p    = pids[node];
    const fvec4* src = reinterpret_cast<const fvec4*>(h + (size_t)node * DCONST + seg * 8);
    fvec4 a = src[0];
    fvec4 b = src[1];
    bf16x8 v;
    v[0] = (__bf16)a[0]; v[1] = (__bf16)a[1]; v[2] = (__bf16)a[2]; v[3] = (__bf16)a[3];
    v[4] = (__bf16)b[0]; v[5] = (__bf16)b[1]; v[6] = (__bf16)b[2]; v[7] = (__bf16)b[3];
    *reinterpret_cast<bf16x8*>(padded + ((size_t)g * MAXN + p) * DCONST + seg * 8) = v;
}

// ---------------------------------------------------------------------------
// Stage 3: per-graph C = X X^T, X = [512][512] bf16 (zero padded), C fp32.
// Block: one 128x128 tile of one graph. 256 threads = 4 waves (2x2),
// each wave owns 64x64 = 4x4 frags of mfma_f32_16x16x32_bf16.
// BK=64, double-buffered LDS staged via global_load_lds(16B) with
// pre-swizzled global source:  physical slot s of row r holds chunk s^(r&7).
// ---------------------------------------------------------------------------
__global__ __launch_bounds__(256, 2) void gemm_xxt(const __bf16* __restrict__ X,
                                                   float* __restrict__ out)
{
    __shared__ __align__(16) __bf16 lds[2][2][128][64];   // [dbuf][A,B][row][k] = 64 KiB

    const int bid = blockIdx.x;
    // XCD-aware mapping: blocks round-robin XCDs; give each XCD 8 whole graphs
    // so a graph's 512KiB X panel stays in one 4MiB L2.
    const int xcd = bid & 7;
    const int ixc = bid >> 3;              // 0..127
    const int g   = xcd * 8 + (ixc >> 4);  // 8 graphs per XCD
    const int tl  = ixc & 15;              // 16 tiles per graph
    const int row0 = (tl >> 2) * 128;
    const int col0 = (tl & 3) * 128;

    const __bf16* __restrict__ Xg = X + (size_t)g * MAXN * DCONST;

    const int tid  = threadIdx.x;
    const int wave = tid >> 6;
    const int lane = tid & 63;
    const int wr   = wave >> 1;            // wave row 0..1
    const int wc   = wave & 1;             // wave col 0..1

    f32x4 acc[4][4] = {};

    const int srow  = lane >> 3;           // 0..7 (row within 8-row wave chunk)
    const int sslot = lane & 7;            // 16B slot within 128B row

    auto stage = [&](int buf, int kt) {
        const int k0 = kt * 64;
        #pragma unroll
        for (int r = 0; r < 4; ++r) {
            const int rbase = wave * 8 + r * 32;       // wave-uniform
            const int rr    = rbase + srow;            // per-lane row
            const int chunk = sslot ^ (rr & 7);        // inverse swizzle on SOURCE
            const __bf16* gA = Xg + (size_t)(row0 + rr) * DCONST + k0 + chunk * 8;
            __builtin_amdgcn_global_load_lds(gA, &lds[buf][0][rbase][0], 16, 0, 0);
            const __bf16* gB = Xg + (size_t)(col0 + rr) * DCONST + k0 + chunk * 8;
            __builtin_amdgcn_global_load_lds(gB, &lds[buf][1][rbase][0], 16, 0, 0);
        }
    };

    stage(0, 0);
    asm volatile("s_waitcnt vmcnt(0)" ::: "memory");
    __syncthreads();

    int cur = 0;
    const int fr = lane & 15;              // frag row/col within 16
    const int q  = lane >> 4;              // k-quarter 0..3

    #pragma unroll
    for (int kt = 0; kt < 8; ++kt) {
        if (kt < 7) stage(cur ^ 1, kt + 1);

        bf16x8 afr[2][4], bfr[2][4];
        #pragma unroll
        for (int ks = 0; ks < 2; ++ks) {
            const int chunk = ks * 4 + q;
            #pragma unroll
            for (int m = 0; m < 4; ++m) {
                const int rr   = wr * 64 + m * 16 + fr;
                const int slot = chunk ^ (rr & 7);     // swizzled READ
                afr[ks][m] = *reinterpret_cast<const bf16x8*>(&lds[cur][0][rr][slot * 8]);
            }
            #pragma unroll
            for (int n = 0; n < 4; ++n) {
                const int rr   = wc * 64 + n * 16 + fr;
                const int slot = chunk ^ (rr & 7);
                bfr[ks][n] = *reinterpret_cast<const bf16x8*>(&lds[cur][1][rr][slot * 8]);
            }
        }

        #pragma unroll
        for (int ks = 0; ks < 2; ++ks)
            #pragma unroll
            for (int m = 0; m < 4; ++m)
                #pragma unroll
                for (int n = 0; n < 4; ++n)
                    acc[m][n] = __builtin_amdgcn_mfma_f32_16x16x32_bf16(
                        afr[ks][m], bfr[ks][n], acc[m][n], 0, 0, 0);

        if (kt < 7) {
            asm volatile("s_waitcnt vmcnt(0)" ::: "memory");
            __syncthreads();
        }
        cur ^= 1;
    }

    // Epilogue: C/D layout col = lane&15, row = (lane>>4)*4 + reg  [m89-verified]
    float* __restrict__ og = out + (size_t)g * MAXN * MAXN;
    const int rowb = row0 + wr * 64 + q * 4;
    const int colb = col0 + wc * 64 + fr;
    #pragma unroll
    for (int m = 0; m < 4; ++m) {
        #pragma unroll
        for (int n = 0; n < 4; ++n) {
            f32x4 v = acc[m][n];
            float* p = og + (size_t)(rowb + m * 16) * MAXN + colb + n * 16;
            #pragma unroll
            for (int r = 0; r < 4; ++r)
                p[(size_t)r * MAXN] = v[r];
        }
    }
}

// ---------------------------------------------------------------------------
extern "C" void kernel_launch(void* const* d_in, const int* in_sizes, int n_in,
                              void* d_out, int out_size, void* d_ws, size_t ws_size,
                              hipStream_t stream)
{
    const float* h    = (const float*)d_in[0];
    const int*   gids = (const int*)d_in[1];
    const int*   pids = (const int*)d_in[2];
    const int    total = in_sizes[1];

    __bf16* padded = (__bf16*)d_ws;
    float*  out    = (float*)d_out;

    // Stage 1: zero the padded buffer (ws is re-poisoned to 0xAA every call)
    hipMemsetAsync(d_ws, 0, (size_t)NGRAPH * MAXN * DCONST * sizeof(__bf16), stream);

    // Stage 2: scatter + fp32->bf16
    const int sthreads = total * 64;
    scatter_bf16<<<(sthreads + 255) / 256, 256, 0, stream>>>(h, gids, pids, padded, total);

    // Stage 3: batched Gram matrices
    gemm_xxt<<<dim3(NGRAPH * 16), dim3(256), 0, stream>>>(padded, out);
}